// Round 6
// baseline (468.222 us; speedup 1.0000x reference)
//
#include <hip/hip_runtime.h>

#define N_NODES 50000
#define N_PAD   50048          // padded row count (multiple of 128)
#define N_EDGES 800000
#define IN_DIM 128
#define HIDDEN 256
#define N_CLASSES 10
#define N_GRAPHS 64

#define SCAN_BLK 1024
#define NB_SCAN ((N_NODES + SCAN_BLK - 1) / SCAN_BLK)   // 49

typedef __attribute__((ext_vector_type(8))) short short8;
typedef __attribute__((ext_vector_type(4))) float f32x4;

// Feature-blocked layout FB32: buf[slice][N_PAD][32] bf16, slice = col/32.
// Element (row, col) lives at ((col>>5)*N_PAD + row)*32 + (col&31).

__device__ __forceinline__ float bf2f(unsigned short h) {
    union { unsigned int u; float f; } v; v.u = ((unsigned int)h) << 16; return v.f;
}
__device__ __forceinline__ unsigned short f2bf(float f) {
    union { float f; unsigned int u; } v; v.f = f;
    unsigned int u = v.u;
    u += 0x7FFFu + ((u >> 16) & 1u);   // round to nearest even
    return (unsigned short)(u >> 16);
}

// ---------------- degree count ----------------
__global__ void deg_count_kernel(const int* __restrict__ src, int* __restrict__ deg) {
    int e = blockIdx.x * blockDim.x + threadIdx.x;
    if (e < N_EDGES) atomicAdd(&deg[src[e]], 1);
}

// ---------------- multi-block scan, phase A: per-block sums ----------------
__global__ __launch_bounds__(SCAN_BLK)
void block_sum_kernel(const int* __restrict__ deg, int* __restrict__ blocksum) {
    __shared__ int red[SCAN_BLK / 64];
    int i = blockIdx.x * SCAN_BLK + threadIdx.x;
    int v = (i < N_NODES) ? deg[i] : 0;
    #pragma unroll
    for (int off = 32; off; off >>= 1) v += __shfl_down(v, off, 64);
    if ((threadIdx.x & 63) == 0) red[threadIdx.x >> 6] = v;
    __syncthreads();
    if (threadIdx.x < 64) {
        int s = (threadIdx.x < SCAN_BLK / 64) ? red[threadIdx.x] : 0;
        #pragma unroll
        for (int off = 8; off; off >>= 1) s += __shfl_down(s, off, 64);
        if (threadIdx.x == 0) blocksum[blockIdx.x] = s;
    }
}

// ---------------- phase B: exclusive scan of block sums (one wave) ----------------
__global__ void block_offset_kernel(const int* __restrict__ blocksum, int* __restrict__ blockoff) {
    int lane = threadIdx.x;   // 64 threads
    int v = (lane < NB_SCAN) ? blocksum[lane] : 0;
    #pragma unroll
    for (int off = 1; off < 64; off <<= 1) {
        int t = __shfl_up(v, off, 64);
        if (lane >= off) v += t;
    }
    int ex = __shfl_up(v, 1, 64);
    if (lane == 0) ex = 0;
    if (lane < NB_SCAN) blockoff[lane] = ex;
}

// ---------------- phase C: local scan + outputs ----------------
__global__ __launch_bounds__(SCAN_BLK)
void scan_phase_c_kernel(const int* __restrict__ deg, const int* __restrict__ blockoff,
                         int* __restrict__ rowptr, int* __restrict__ cursor,
                         float* __restrict__ rdeg,
                         int* __restrict__ d0cnt, int* __restrict__ d0list) {
    __shared__ int buf[SCAN_BLK];
    int i = blockIdx.x * SCAN_BLK + threadIdx.x;
    int v = (i < N_NODES) ? deg[i] : 0;
    buf[threadIdx.x] = v;
    __syncthreads();
    #pragma unroll
    for (int off = 1; off < SCAN_BLK; off <<= 1) {
        int t = (threadIdx.x >= off) ? buf[threadIdx.x - off] : 0;
        __syncthreads();
        buf[threadIdx.x] += t;
        __syncthreads();
    }
    int incl = buf[threadIdx.x] + blockoff[blockIdx.x];
    if (i < N_NODES) {
        rowptr[i + 1] = incl;
        cursor[i] = incl - v;
        rdeg[i] = (v > 0) ? 1.0f / (float)v : 0.0f;
        if (v == 0) { int p = atomicAdd(d0cnt, 1); d0list[p] = i; }
        if (i == 0) rowptr[0] = 0;
    }
}

// ---------------- CSR fill ----------------
__global__ void csr_fill_kernel(const int* __restrict__ src, const int* __restrict__ dst,
                                int* __restrict__ cursor, int* __restrict__ csr) {
    int e = blockIdx.x * blockDim.x + threadIdx.x;
    if (e < N_EDGES) {
        int p = atomicAdd(&cursor[src[e]], 1);
        csr[p] = dst[e];
    }
}

// ---------------- fp32 row-major -> bf16 FB32 ----------------
__global__ void cvt_bf16_fb_kernel(const float* __restrict__ in, unsigned short* __restrict__ out) {
    int i = blockIdx.x * blockDim.x + threadIdx.x;   // one thread per 8 elements
    if (i >= N_NODES * (IN_DIM / 8)) return;
    int n = i >> 4, c = i & 15;                       // c: which 8-col chunk of the row
    const float4* p = reinterpret_cast<const float4*>(in + (size_t)n * IN_DIM + c * 8);
    float4 v0 = p[0], v1 = p[1];
    uint4 o;
    o.x = (unsigned int)f2bf(v0.x) | ((unsigned int)f2bf(v0.y) << 16);
    o.y = (unsigned int)f2bf(v0.z) | ((unsigned int)f2bf(v0.w) << 16);
    o.z = (unsigned int)f2bf(v1.x) | ((unsigned int)f2bf(v1.y) << 16);
    o.w = (unsigned int)f2bf(v1.z) | ((unsigned int)f2bf(v1.w) << 16);
    // dest: slice = c>>2, within-slice offset (c&3)*8
    *reinterpret_cast<uint4*>(out + ((size_t)(c >> 2) * N_PAD + n) * 32 + (c & 3) * 8) = o;
}

// ---------------- weight prep: Wt[c][k] = bf16( k<D ? Wg[k][c]+Ws[k][c] : Wl[k-D][c] ) ----------------
template<int D>
__global__ void prep_w_kernel(const float* __restrict__ Wg, const float* __restrict__ Wl,
                              const float* __restrict__ Ws, unsigned short* __restrict__ Wt) {
    int i = blockIdx.x * blockDim.x + threadIdx.x;
    if (i >= 256 * 2 * D) return;
    int c = i / (2 * D), k = i % (2 * D);
    float v;
    if (k < D) v = Wg[(size_t)k * 256 + c] + Ws[(size_t)k * 256 + c];
    else       v = Wl[(size_t)(k - D) * 256 + c];
    Wt[i] = f2bf(v);
}

// ---------------- XCD-partitioned gather-mean over FB32 ----------------
// grid (8, chunks): blockIdx.x (dispatch round-robin -> XCD) picks the feature
// slice, so each XCD's L2 only holds one 3.2 MB slice. 4 waves/block, 32
// nodes/wave; per node the wave's four 16-lane groups each process every 4th
// edge, reading a 64B slice-row; shfl_xor(16/32) reduces groups.
template<int D>
__global__ __launch_bounds__(256)
void gather_slice_kernel(const int* __restrict__ rowptr, const int* __restrict__ csr,
                         const float* __restrict__ rdeg,
                         const unsigned short* __restrict__ H, unsigned short* __restrict__ NS) {
    constexpr int NSL = D / 32, SUB = 8 / NSL;
    const int slice = blockIdx.x / SUB;
    const int chunk = blockIdx.y * SUB + (blockIdx.x % SUB);
    const int lane = threadIdx.x & 63;
    const int grp = lane >> 4, s16 = lane & 15;
    const unsigned int* Hu = reinterpret_cast<const unsigned int*>(H) + (size_t)slice * N_PAD * 16;
    unsigned int* Ou = reinterpret_cast<unsigned int*>(NS) + (size_t)slice * N_PAD * 16;
    const int nodebase = chunk * 128 + (threadIdx.x >> 6) * 32;
    for (int i = 0; i < 32; ++i) {
        int node = nodebase + i;
        if (node >= N_NODES) return;
        int lo = rowptr[node], hi = rowptr[node + 1];
        float a0 = 0.f, a1 = 0.f;
        for (int j = lo + grp; j < hi; j += 4) {
            unsigned int v = Hu[(size_t)csr[j] * 16 + s16];
            a0 += bf2f(v & 0xFFFF); a1 += bf2f(v >> 16);
        }
        a0 += __shfl_xor(a0, 16, 64); a0 += __shfl_xor(a0, 32, 64);
        a1 += __shfl_xor(a1, 16, 64); a1 += __shfl_xor(a1, 32, 64);
        if (grp == 0) {
            float r = rdeg[node];
            Ou[(size_t)node * 16 + s16] =
                (unsigned int)f2bf(a0 * r) | ((unsigned int)f2bf(a1 * r) << 16);
        }
    }
}

// ---------------- MFMA GEMM: OUT = elu( [X|NS] @ Wt^T + b ) ----------------
// X, NS in FB32; OUT blocked (layer0 -> h1) or row-major (layer1 -> h2)
template<int D, bool BLK_OUT>
__global__ __launch_bounds__(512)
void gemm_mfma_kernel(const unsigned short* __restrict__ X, const unsigned short* __restrict__ NS,
                      const unsigned short* __restrict__ Wt, const float* __restrict__ bias,
                      unsigned short* __restrict__ OUT) {
    constexpr int KTOT = 2 * D;
    __shared__ __align__(16) unsigned short A_lds[128 * 64];
    __shared__ __align__(16) unsigned short B_lds[256 * 64];
    const int tid = threadIdx.x;
    const int lane = tid & 63;
    const int wid = tid >> 6;
    const int wm = wid >> 2, wn = wid & 3;
    const int rowbase = blockIdx.x * 128;

    f32x4 acc[4][4];
    #pragma unroll
    for (int i = 0; i < 4; ++i)
        #pragma unroll
        for (int j = 0; j < 4; ++j) acc[i][j] = (f32x4)0.0f;

    for (int kt = 0; kt < KTOT; kt += 64) {
        const unsigned short* Aseg = (kt < D) ? X : NS;
        const int kd0 = (kt < D) ? kt : kt - D;
        #pragma unroll
        for (int p = 0; p < 2; ++p) {
            int c = (p * 8 + wid) * 64 + lane;
            int row = c >> 3, sl = c & 7;
            int ss = sl ^ (row & 7);
            int gc = kd0 + ss * 8;                    // global col of this 8-half chunk
            const unsigned short* g = Aseg + ((size_t)(gc >> 5) * N_PAD + rowbase + row) * 32 + (gc & 31);
            unsigned short* l = &A_lds[(size_t)(p * 8 + wid) * 512];
            __builtin_amdgcn_global_load_lds((const __attribute__((address_space(1))) unsigned int*)g,
                                             (__attribute__((address_space(3))) unsigned int*)l, 16, 0, 0);
        }
        #pragma unroll
        for (int p = 0; p < 4; ++p) {
            int c = (p * 8 + wid) * 64 + lane;
            int br = c >> 3, sl = c & 7;
            int ss = sl ^ (br & 7);
            const unsigned short* g = Wt + (size_t)br * KTOT + kt + ss * 8;
            unsigned short* l = &B_lds[(size_t)(p * 8 + wid) * 512];
            __builtin_amdgcn_global_load_lds((const __attribute__((address_space(1))) unsigned int*)g,
                                             (__attribute__((address_space(3))) unsigned int*)l, 16, 0, 0);
        }
        __syncthreads();
        #pragma unroll
        for (int ks = 0; ks < 2; ++ks) {
            short8 a[4], b[4];
            int s = ks * 4 + (lane >> 4);
            #pragma unroll
            for (int f = 0; f < 4; ++f) {
                int row = wm * 64 + f * 16 + (lane & 15);
                a[f] = *reinterpret_cast<const short8*>(&A_lds[row * 64 + ((s ^ (row & 7)) << 3)]);
                int col = wn * 64 + f * 16 + (lane & 15);
                b[f] = *reinterpret_cast<const short8*>(&B_lds[col * 64 + ((s ^ (col & 7)) << 3)]);
            }
            #pragma unroll
            for (int fi = 0; fi < 4; ++fi)
                #pragma unroll
                for (int fj = 0; fj < 4; ++fj)
                    acc[fi][fj] = __builtin_amdgcn_mfma_f32_16x16x32_bf16(a[fi], b[fj], acc[fi][fj], 0, 0, 0);
        }
        __syncthreads();
    }

    float bv[4];
    #pragma unroll
    for (int fj = 0; fj < 4; ++fj) bv[fj] = bias[wn * 64 + fj * 16 + (lane & 15)];
    #pragma unroll
    for (int fi = 0; fi < 4; ++fi) {
        #pragma unroll
        for (int r = 0; r < 4; ++r) {
            int row = rowbase + wm * 64 + fi * 16 + (lane >> 4) * 4 + r;
            if (row < N_NODES) {
                #pragma unroll
                for (int fj = 0; fj < 4; ++fj) {
                    int col = wn * 64 + fj * 16 + (lane & 15);
                    float z = acc[fi][fj][r] + bv[fj];
                    z = z > 0.f ? z : (expf(z) - 1.f);
                    if (BLK_OUT)
                        OUT[((size_t)(col >> 5) * N_PAD + row) * 32 + (col & 31)] = f2bf(z);
                    else
                        OUT[(size_t)row * 256 + col] = f2bf(z);
                }
            }
        }
    }
}

// ---------------- fixup for degree-0 rows: OUT[row] = elu(X[row] @ Wg + b) ----------------
// XF32: X is fp32 row-major; else X is bf16 FB32. BLK_OUT as in gemm.
template<bool XF32, bool BLK_OUT, int D>
__global__ void fixup_kernel(const int* __restrict__ cnt, const int* __restrict__ list,
                             const void* __restrict__ X,
                             const float* __restrict__ Wg, const float* __restrict__ bias,
                             unsigned short* __restrict__ OUT) {
    int c = threadIdx.x;
    int n = *cnt;
    for (int i = blockIdx.x; i < n; i += gridDim.x) {
        int row = list[i];
        float acc = bias[c];
        for (int k = 0; k < D; ++k) {
            float xv;
            if constexpr (XF32) xv = ((const float*)X)[(size_t)row * D + k];
            else xv = bf2f(((const unsigned short*)X)[((size_t)(k >> 5) * N_PAD + row) * 32 + (k & 31)]);
            acc = fmaf(xv, Wg[(size_t)k * 256 + c], acc);
        }
        acc = acc > 0.f ? acc : (expf(acc) - 1.f);
        if (BLK_OUT) OUT[((size_t)(c >> 5) * N_PAD + row) * 32 + (c & 31)] = f2bf(acc);
        else         OUT[(size_t)row * 256 + c] = f2bf(acc);
    }
}

// ---------------- pooling stage 1: per-block segmented accumulate -> atomicAdd ----------------
__global__ __launch_bounds__(256)
void pool_partial_kernel(const unsigned short* __restrict__ H, const int* __restrict__ batch,
                         float* __restrict__ pooled) {
    const int base = blockIdx.x * 64;
    const int t = threadIdx.x;
    float acc = 0.0f;
    int cur = batch[base];
    const int end = (base + 64 < N_NODES) ? base + 64 : N_NODES;
    for (int r = base; r < end; ++r) {
        int g = batch[r];
        if (g != cur) {
            atomicAdd(&pooled[cur * HIDDEN + t], acc);
            acc = 0.0f; cur = g;
        }
        acc += bf2f(H[(size_t)r * HIDDEN + t]);
    }
    atomicAdd(&pooled[cur * HIDDEN + t], acc);
}

// ---------------- pooling stage 2: divide + classifier ----------------
__global__ void classify_kernel(const float* __restrict__ pooled, const int* __restrict__ batch,
                                const float* __restrict__ Wc, const float* __restrict__ bc,
                                float* __restrict__ out) {
    __shared__ int s_lo, s_hi;
    __shared__ float pl[HIDDEN];
    int g = blockIdx.x;
    if (threadIdx.x == 0) {
        int lo = 0, hi = N_NODES;
        while (lo < hi) { int m = (lo + hi) >> 1; if (batch[m] < g) lo = m + 1; else hi = m; }
        s_lo = lo;
        int lo2 = lo, hi2 = N_NODES;
        while (lo2 < hi2) { int m = (lo2 + hi2) >> 1; if (batch[m] < g + 1) lo2 = m + 1; else hi2 = m; }
        s_hi = lo2;
    }
    __syncthreads();
    int t = threadIdx.x;
    float cnt = (float)(s_hi - s_lo);
    pl[t] = pooled[g * HIDDEN + t] / fmaxf(cnt, 1.0f);
    __syncthreads();
    if (t < N_CLASSES) {
        float accv = bc[t];
        #pragma unroll 4
        for (int k = 0; k < HIDDEN; ++k) accv = fmaf(pl[k], Wc[k * N_CLASSES + t], accv);
        out[g * N_CLASSES + t] = accv;
    }
}

extern "C" void kernel_launch(void* const* d_in, const int* in_sizes, int n_in,
                              void* d_out, int out_size, void* d_ws, size_t ws_size,
                              hipStream_t stream) {
    const float* x    = (const float*)d_in[0];
    const int*   ei   = (const int*)d_in[1];
    const int*   batch= (const int*)d_in[2];
    const float* Wg0  = (const float*)d_in[3];
    const float* Wl0  = (const float*)d_in[4];
    const float* Ws0  = (const float*)d_in[5];
    const float* b0   = (const float*)d_in[6];
    const float* Wg1  = (const float*)d_in[7];
    const float* Wl1  = (const float*)d_in[8];
    const float* Ws1  = (const float*)d_in[9];
    const float* b1   = (const float*)d_in[10];
    const float* Wc   = (const float*)d_in[11];
    const float* bc   = (const float*)d_in[12];
    const int* src = ei;
    const int* dst = ei + N_EDGES;

    char* ws = (char*)d_ws;
    int*            deg    = (int*)(ws + 0);               // [N_PAD]
    int*            d0cnt  = (int*)(ws + 200192);          // 1 int (inside memset region)
    int*            blocksum = (int*)(ws + 200704);        // [49]
    int*            blockoff = (int*)(ws + 201216);        // [49]
    float*          rdeg   = (float*)(ws + 262144);
    int*            rowptr = (int*)(ws + 524288);
    int*            cursor = (int*)(ws + 786432);          // dead after csr_fill
    float*          pooled = (float*)(ws + 786432);        // aliases cursor: f32[64*256] = 64KB
    int*            csr    = (int*)(ws + 1048576);         // [800000]
    int*            d0list = (int*)(ws + 4259840);         // [50000]
    unsigned short* x_bf   = (unsigned short*)(ws + 4521984);    // FB32 [4][N_PAD][32]
    unsigned short* ns0_bf = (unsigned short*)(ws + 17334272);   // FB32 [4][N_PAD][32]
    unsigned short* h1_bf  = (unsigned short*)(ws + 30146560);   // FB32 [8][N_PAD][32]
    unsigned short* ns1_bf = (unsigned short*)(ws + 55771136);   // FB32 [8][N_PAD][32]
    unsigned short* h2_bf  = (unsigned short*)(ws + 81395712);   // row-major [N_PAD][256]
    unsigned short* Wt0    = (unsigned short*)(ws + 107020288);  // [256][256]
    unsigned short* Wt1    = (unsigned short*)(ws + 107151360);  // [256][512]

    // zero degree counts + d0cnt
    hipMemsetAsync(ws, 0, 262144, stream);

    // CSR build (multi-block scan)
    deg_count_kernel<<<(N_EDGES + 255) / 256, 256, 0, stream>>>(src, deg);
    block_sum_kernel<<<NB_SCAN, SCAN_BLK, 0, stream>>>(deg, blocksum);
    block_offset_kernel<<<1, 64, 0, stream>>>(blocksum, blockoff);
    scan_phase_c_kernel<<<NB_SCAN, SCAN_BLK, 0, stream>>>(deg, blockoff, rowptr, cursor, rdeg, d0cnt, d0list);
    csr_fill_kernel<<<(N_EDGES + 255) / 256, 256, 0, stream>>>(src, dst, cursor, csr);

    // weight prep + x conversion (to FB32)
    prep_w_kernel<IN_DIM><<<(256 * 2 * IN_DIM + 255) / 256, 256, 0, stream>>>(Wg0, Wl0, Ws0, Wt0);
    prep_w_kernel<HIDDEN><<<(256 * 2 * HIDDEN + 255) / 256, 256, 0, stream>>>(Wg1, Wl1, Ws1, Wt1);
    cvt_bf16_fb_kernel<<<(N_NODES * 16 + 255) / 256, 256, 0, stream>>>(x, x_bf);

    // layer 0: gather (4 slices, XCD-pinned) -> ns0, GEMM -> h1 (FB32)
    gather_slice_kernel<IN_DIM><<<dim3(8, 196), 256, 0, stream>>>(rowptr, csr, rdeg, x_bf, ns0_bf);
    gemm_mfma_kernel<IN_DIM, true><<<(N_NODES + 127) / 128, 512, 0, stream>>>(x_bf, ns0_bf, Wt0, b0, h1_bf);
    fixup_kernel<true, true, IN_DIM><<<64, 256, 0, stream>>>(d0cnt, d0list, x, Wg0, b0, h1_bf);

    // layer 1: gather (8 slices, XCD-pinned) -> ns1, GEMM -> h2 (row-major)
    gather_slice_kernel<HIDDEN><<<dim3(8, 391), 256, 0, stream>>>(rowptr, csr, rdeg, h1_bf, ns1_bf);
    gemm_mfma_kernel<HIDDEN, false><<<(N_NODES + 127) / 128, 512, 0, stream>>>(h1_bf, ns1_bf, Wt1, b1, h2_bf);
    fixup_kernel<false, false, HIDDEN><<<64, 256, 0, stream>>>(d0cnt, d0list, h1_bf, Wg1, b1, h2_bf);

    // pool (cursor buffer is dead by now; pooled aliases it)
    hipMemsetAsync(pooled, 0, N_GRAPHS * HIDDEN * sizeof(float), stream);
    pool_partial_kernel<<<(N_NODES + 63) / 64, 256, 0, stream>>>(h2_bf, batch, pooled);
    classify_kernel<<<N_GRAPHS, HIDDEN, 0, stream>>>(pooled, batch, Wc, bc, (float*)d_out);
}

// Round 7
// 280.795 us; speedup vs baseline: 1.6675x; 1.6675x over previous
//
#include <hip/hip_runtime.h>

#define N_NODES 50000
#define N_PAD   50048          // padded row count (multiple of 128)
#define N_EDGES 800000
#define IN_DIM 128
#define HIDDEN 256
#define N_CLASSES 10
#define N_GRAPHS 64

#define SCAN_BLK 1024
#define NB_SCAN ((N_NODES + SCAN_BLK - 1) / SCAN_BLK)   // 49

typedef __attribute__((ext_vector_type(8))) short short8;
typedef __attribute__((ext_vector_type(4))) float f32x4;

__device__ __forceinline__ float bf2f(unsigned short h) {
    union { unsigned int u; float f; } v; v.u = ((unsigned int)h) << 16; return v.f;
}
__device__ __forceinline__ unsigned short f2bf(float f) {
    union { float f; unsigned int u; } v; v.f = f;
    unsigned int u = v.u;
    u += 0x7FFFu + ((u >> 16) & 1u);   // round to nearest even
    return (unsigned short)(u >> 16);
}

// ---------------- degree count ----------------
__global__ void deg_count_kernel(const int* __restrict__ src, int* __restrict__ deg) {
    int e = blockIdx.x * blockDim.x + threadIdx.x;
    if (e < N_EDGES) atomicAdd(&deg[src[e]], 1);
}

// ---------------- multi-block scan, phase A: per-block sums ----------------
__global__ __launch_bounds__(SCAN_BLK)
void block_sum_kernel(const int* __restrict__ deg, int* __restrict__ blocksum) {
    __shared__ int red[SCAN_BLK / 64];
    int i = blockIdx.x * SCAN_BLK + threadIdx.x;
    int v = (i < N_NODES) ? deg[i] : 0;
    #pragma unroll
    for (int off = 32; off; off >>= 1) v += __shfl_down(v, off, 64);
    if ((threadIdx.x & 63) == 0) red[threadIdx.x >> 6] = v;
    __syncthreads();
    if (threadIdx.x < 64) {
        int s = (threadIdx.x < SCAN_BLK / 64) ? red[threadIdx.x] : 0;
        #pragma unroll
        for (int off = 8; off; off >>= 1) s += __shfl_down(s, off, 64);
        if (threadIdx.x == 0) blocksum[blockIdx.x] = s;
    }
}

// ---------------- phase B: exclusive scan of block sums (one wave) ----------------
__global__ void block_offset_kernel(const int* __restrict__ blocksum, int* __restrict__ blockoff) {
    int lane = threadIdx.x;   // 64 threads
    int v = (lane < NB_SCAN) ? blocksum[lane] : 0;
    #pragma unroll
    for (int off = 1; off < 64; off <<= 1) {
        int t = __shfl_up(v, off, 64);
        if (lane >= off) v += t;
    }
    int ex = __shfl_up(v, 1, 64);
    if (lane == 0) ex = 0;
    if (lane < NB_SCAN) blockoff[lane] = ex;
}

// ---------------- phase C: local scan + outputs ----------------
__global__ __launch_bounds__(SCAN_BLK)
void scan_phase_c_kernel(const int* __restrict__ deg, const int* __restrict__ blockoff,
                         int* __restrict__ rowptr, int* __restrict__ cursor,
                         float* __restrict__ rdeg,
                         int* __restrict__ d0cnt, int* __restrict__ d0list) {
    __shared__ int buf[SCAN_BLK];
    int i = blockIdx.x * SCAN_BLK + threadIdx.x;
    int v = (i < N_NODES) ? deg[i] : 0;
    buf[threadIdx.x] = v;
    __syncthreads();
    #pragma unroll
    for (int off = 1; off < SCAN_BLK; off <<= 1) {
        int t = (threadIdx.x >= off) ? buf[threadIdx.x - off] : 0;
        __syncthreads();
        buf[threadIdx.x] += t;
        __syncthreads();
    }
    int incl = buf[threadIdx.x] + blockoff[blockIdx.x];
    if (i < N_NODES) {
        rowptr[i + 1] = incl;
        cursor[i] = incl - v;
        rdeg[i] = (v > 0) ? 1.0f / (float)v : 0.0f;
        if (v == 0) { int p = atomicAdd(d0cnt, 1); d0list[p] = i; }
        if (i == 0) rowptr[0] = 0;
    }
}

// ---------------- CSR fill ----------------
__global__ void csr_fill_kernel(const int* __restrict__ src, const int* __restrict__ dst,
                                int* __restrict__ cursor, int* __restrict__ csr) {
    int e = blockIdx.x * blockDim.x + threadIdx.x;
    if (e < N_EDGES) {
        int p = atomicAdd(&cursor[src[e]], 1);
        csr[p] = dst[e];
    }
}

// ---------------- fp32 -> bf16 convert (4 at a time) ----------------
__global__ void cvt_bf16_kernel(const float* __restrict__ in, unsigned short* __restrict__ out, int n4) {
    int i = blockIdx.x * blockDim.x + threadIdx.x;
    if (i >= n4) return;
    float4 v = reinterpret_cast<const float4*>(in)[i];
    ushort4 o;
    o.x = f2bf(v.x); o.y = f2bf(v.y); o.z = f2bf(v.z); o.w = f2bf(v.w);
    reinterpret_cast<ushort4*>(out)[i] = o;
}

// ---------------- weight prep: Wt[c][k] = bf16( k<D ? Wg[k][c]+Ws[k][c] : Wl[k-D][c] ) ----------------
template<int D>
__global__ void prep_w_kernel(const float* __restrict__ Wg, const float* __restrict__ Wl,
                              const float* __restrict__ Ws, unsigned short* __restrict__ Wt) {
    int i = blockIdx.x * blockDim.x + threadIdx.x;
    if (i >= 256 * 2 * D) return;
    int c = i / (2 * D), k = i % (2 * D);
    float v;
    if (k < D) v = Wg[(size_t)k * 256 + c] + Ws[(size_t)k * 256 + c];
    else       v = Wl[(size_t)(k - D) * 256 + c];
    Wt[i] = f2bf(v);
}

// ---------------- gather mean (bf16 row-major), one wave per node, uint4/lane ----------------
// D=256: 32 lanes cover a 512B row, 2 edges/iter; D=128: 16 lanes cover 256B, 4 edges/iter.
// Unroll 2 wave-iterations for MLP. Cross-edge-slot reduce via shfl_xor.
template<int D>
__global__ __launch_bounds__(256)
void gather_mean_kernel(const int* __restrict__ rowptr, const int* __restrict__ csr,
                        const float* __restrict__ rdeg,
                        const unsigned short* __restrict__ H, unsigned short* __restrict__ NS) {
    constexpr int LPR = D / 8;        // lanes per row (16 B each): 32 or 16
    constexpr int EPW = 64 / LPR;     // edge slots per wave: 2 or 4
    int node = blockIdx.x * 4 + (threadIdx.x >> 6);
    if (node >= N_NODES) return;
    const int lane = threadIdx.x & 63;
    const int sub = lane / LPR;       // edge slot
    const int sl  = lane % LPR;       // 16B chunk within row
    const int lo = rowptr[node], hi = rowptr[node + 1];
    const uint4* H4 = reinterpret_cast<const uint4*>(H);
    float a0=0.f,a1=0.f,a2=0.f,a3=0.f,a4=0.f,a5=0.f,a6=0.f,a7=0.f;
    int j = lo;
    for (; j + 2 * EPW <= hi; j += 2 * EPW) {
        int d0 = csr[j + sub], d1 = csr[j + EPW + sub];
        uint4 v0 = H4[(size_t)d0 * LPR + sl];
        uint4 v1 = H4[(size_t)d1 * LPR + sl];
        a0 += bf2f(v0.x & 0xFFFF) + bf2f(v1.x & 0xFFFF);
        a1 += bf2f(v0.x >> 16)    + bf2f(v1.x >> 16);
        a2 += bf2f(v0.y & 0xFFFF) + bf2f(v1.y & 0xFFFF);
        a3 += bf2f(v0.y >> 16)    + bf2f(v1.y >> 16);
        a4 += bf2f(v0.z & 0xFFFF) + bf2f(v1.z & 0xFFFF);
        a5 += bf2f(v0.z >> 16)    + bf2f(v1.z >> 16);
        a6 += bf2f(v0.w & 0xFFFF) + bf2f(v1.w & 0xFFFF);
        a7 += bf2f(v0.w >> 16)    + bf2f(v1.w >> 16);
    }
    for (; j + sub < hi; j += EPW) {
        uint4 v0 = H4[(size_t)csr[j + sub] * LPR + sl];
        a0 += bf2f(v0.x & 0xFFFF);
        a1 += bf2f(v0.x >> 16);
        a2 += bf2f(v0.y & 0xFFFF);
        a3 += bf2f(v0.y >> 16);
        a4 += bf2f(v0.z & 0xFFFF);
        a5 += bf2f(v0.z >> 16);
        a6 += bf2f(v0.w & 0xFFFF);
        a7 += bf2f(v0.w >> 16);
    }
    // reduce across edge slots (lanes differing in bits >= log2(LPR))
    #pragma unroll
    for (int off = LPR; off < 64; off <<= 1) {
        a0 += __shfl_xor(a0, off, 64);
        a1 += __shfl_xor(a1, off, 64);
        a2 += __shfl_xor(a2, off, 64);
        a3 += __shfl_xor(a3, off, 64);
        a4 += __shfl_xor(a4, off, 64);
        a5 += __shfl_xor(a5, off, 64);
        a6 += __shfl_xor(a6, off, 64);
        a7 += __shfl_xor(a7, off, 64);
    }
    if (sub == 0) {
        float r = rdeg[node];
        uint4 o;
        o.x = (unsigned int)f2bf(a0 * r) | ((unsigned int)f2bf(a1 * r) << 16);
        o.y = (unsigned int)f2bf(a2 * r) | ((unsigned int)f2bf(a3 * r) << 16);
        o.z = (unsigned int)f2bf(a4 * r) | ((unsigned int)f2bf(a5 * r) << 16);
        o.w = (unsigned int)f2bf(a6 * r) | ((unsigned int)f2bf(a7 * r) << 16);
        reinterpret_cast<uint4*>(NS)[(size_t)node * LPR + sl] = o;
    }
}

// ---------------- MFMA GEMM: OUT = elu( [X|NS] @ Wt^T + b ), Wt is [256][2D] bf16 ----------------
template<int D>
__global__ __launch_bounds__(512)
void gemm_mfma_kernel(const unsigned short* __restrict__ X, const unsigned short* __restrict__ NS,
                      const unsigned short* __restrict__ Wt, const float* __restrict__ bias,
                      unsigned short* __restrict__ OUT) {
    constexpr int KTOT = 2 * D;
    __shared__ __align__(16) unsigned short A_lds[128 * 64];
    __shared__ __align__(16) unsigned short B_lds[256 * 64];
    const int tid = threadIdx.x;
    const int lane = tid & 63;
    const int wid = tid >> 6;
    const int wm = wid >> 2, wn = wid & 3;
    const int rowbase = blockIdx.x * 128;

    f32x4 acc[4][4];
    #pragma unroll
    for (int i = 0; i < 4; ++i)
        #pragma unroll
        for (int j = 0; j < 4; ++j) acc[i][j] = (f32x4)0.0f;

    for (int kt = 0; kt < KTOT; kt += 64) {
        const unsigned short* Aseg = (kt < D) ? X : NS;
        const int kd0 = (kt < D) ? kt : kt - D;
        #pragma unroll
        for (int p = 0; p < 2; ++p) {
            int c = (p * 8 + wid) * 64 + lane;
            int row = c >> 3, sl = c & 7;
            int ss = sl ^ (row & 7);
            const unsigned short* g = Aseg + (size_t)(rowbase + row) * D + kd0 + ss * 8;
            unsigned short* l = &A_lds[(size_t)(p * 8 + wid) * 512];
            __builtin_amdgcn_global_load_lds((const __attribute__((address_space(1))) unsigned int*)g,
                                             (__attribute__((address_space(3))) unsigned int*)l, 16, 0, 0);
        }
        #pragma unroll
        for (int p = 0; p < 4; ++p) {
            int c = (p * 8 + wid) * 64 + lane;
            int br = c >> 3, sl = c & 7;
            int ss = sl ^ (br & 7);
            const unsigned short* g = Wt + (size_t)br * KTOT + kt + ss * 8;
            unsigned short* l = &B_lds[(size_t)(p * 8 + wid) * 512];
            __builtin_amdgcn_global_load_lds((const __attribute__((address_space(1))) unsigned int*)g,
                                             (__attribute__((address_space(3))) unsigned int*)l, 16, 0, 0);
        }
        __syncthreads();
        #pragma unroll
        for (int ks = 0; ks < 2; ++ks) {
            short8 a[4], b[4];
            int s = ks * 4 + (lane >> 4);
            #pragma unroll
            for (int f = 0; f < 4; ++f) {
                int row = wm * 64 + f * 16 + (lane & 15);
                a[f] = *reinterpret_cast<const short8*>(&A_lds[row * 64 + ((s ^ (row & 7)) << 3)]);
                int col = wn * 64 + f * 16 + (lane & 15);
                b[f] = *reinterpret_cast<const short8*>(&B_lds[col * 64 + ((s ^ (col & 7)) << 3)]);
            }
            #pragma unroll
            for (int fi = 0; fi < 4; ++fi)
                #pragma unroll
                for (int fj = 0; fj < 4; ++fj)
                    acc[fi][fj] = __builtin_amdgcn_mfma_f32_16x16x32_bf16(a[fi], b[fj], acc[fi][fj], 0, 0, 0);
        }
        __syncthreads();
    }

    float bv[4];
    #pragma unroll
    for (int fj = 0; fj < 4; ++fj) bv[fj] = bias[wn * 64 + fj * 16 + (lane & 15)];
    #pragma unroll
    for (int fi = 0; fi < 4; ++fi) {
        #pragma unroll
        for (int r = 0; r < 4; ++r) {
            int row = rowbase + wm * 64 + fi * 16 + (lane >> 4) * 4 + r;
            if (row < N_NODES) {
                #pragma unroll
                for (int fj = 0; fj < 4; ++fj) {
                    float z = acc[fi][fj][r] + bv[fj];
                    z = z > 0.f ? z : (expf(z) - 1.f);
                    OUT[(size_t)row * 256 + wn * 64 + fj * 16 + (lane & 15)] = f2bf(z);
                }
            }
        }
    }
}

// ---------------- fixup for degree-0 rows: OUT[row] = elu(X[row] @ Wg + b) ----------------
template<typename T, int D>
__global__ void fixup_kernel(const int* __restrict__ cnt, const int* __restrict__ list,
                             const T* __restrict__ X,
                             const float* __restrict__ Wg, const float* __restrict__ bias,
                             unsigned short* __restrict__ OUT) {
    int c = threadIdx.x;
    int n = *cnt;
    for (int i = blockIdx.x; i < n; i += gridDim.x) {
        int row = list[i];
        float acc = bias[c];
        for (int k = 0; k < D; ++k) {
            float xv;
            if constexpr (sizeof(T) == 4) xv = ((const float*)X)[(size_t)row * D + k];
            else                          xv = bf2f(((const unsigned short*)X)[(size_t)row * D + k]);
            acc = fmaf(xv, Wg[(size_t)k * 256 + c], acc);
        }
        acc = acc > 0.f ? acc : (expf(acc) - 1.f);
        OUT[(size_t)row * 256 + c] = f2bf(acc);
    }
}

// ---------------- pooling stage 1: per-block segmented accumulate -> atomicAdd ----------------
__global__ __launch_bounds__(256)
void pool_partial_kernel(const unsigned short* __restrict__ H, const int* __restrict__ batch,
                         float* __restrict__ pooled) {
    const int base = blockIdx.x * 64;
    const int t = threadIdx.x;
    float acc = 0.0f;
    int cur = batch[base];
    const int end = (base + 64 < N_NODES) ? base + 64 : N_NODES;
    for (int r = base; r < end; ++r) {
        int g = batch[r];
        if (g != cur) {
            atomicAdd(&pooled[cur * HIDDEN + t], acc);
            acc = 0.0f; cur = g;
        }
        acc += bf2f(H[(size_t)r * HIDDEN + t]);
    }
    atomicAdd(&pooled[cur * HIDDEN + t], acc);
}

// ---------------- pooling stage 2: divide + classifier ----------------
__global__ void classify_kernel(const float* __restrict__ pooled, const int* __restrict__ batch,
                                const float* __restrict__ Wc, const float* __restrict__ bc,
                                float* __restrict__ out) {
    __shared__ int s_lo, s_hi;
    __shared__ float pl[HIDDEN];
    int g = blockIdx.x;
    if (threadIdx.x == 0) {
        int lo = 0, hi = N_NODES;
        while (lo < hi) { int m = (lo + hi) >> 1; if (batch[m] < g) lo = m + 1; else hi = m; }
        s_lo = lo;
        int lo2 = lo, hi2 = N_NODES;
        while (lo2 < hi2) { int m = (lo2 + hi2) >> 1; if (batch[m] < g + 1) lo2 = m + 1; else hi2 = m; }
        s_hi = lo2;
    }
    __syncthreads();
    int t = threadIdx.x;
    float cnt = (float)(s_hi - s_lo);
    pl[t] = pooled[g * HIDDEN + t] / fmaxf(cnt, 1.0f);
    __syncthreads();
    if (t < N_CLASSES) {
        float accv = bc[t];
        #pragma unroll 4
        for (int k = 0; k < HIDDEN; ++k) accv = fmaf(pl[k], Wc[k * N_CLASSES + t], accv);
        out[g * N_CLASSES + t] = accv;
    }
}

extern "C" void kernel_launch(void* const* d_in, const int* in_sizes, int n_in,
                              void* d_out, int out_size, void* d_ws, size_t ws_size,
                              hipStream_t stream) {
    const float* x    = (const float*)d_in[0];
    const int*   ei   = (const int*)d_in[1];
    const int*   batch= (const int*)d_in[2];
    const float* Wg0  = (const float*)d_in[3];
    const float* Wl0  = (const float*)d_in[4];
    const float* Ws0  = (const float*)d_in[5];
    const float* b0   = (const float*)d_in[6];
    const float* Wg1  = (const float*)d_in[7];
    const float* Wl1  = (const float*)d_in[8];
    const float* Ws1  = (const float*)d_in[9];
    const float* b1   = (const float*)d_in[10];
    const float* Wc   = (const float*)d_in[11];
    const float* bc   = (const float*)d_in[12];
    const int* src = ei;
    const int* dst = ei + N_EDGES;

    char* ws = (char*)d_ws;
    int*            deg    = (int*)(ws + 0);               // [N_PAD]
    int*            d0cnt  = (int*)(ws + 200192);          // 1 int (inside memset region)
    int*            blocksum = (int*)(ws + 200704);        // [49]
    int*            blockoff = (int*)(ws + 201216);        // [49]
    float*          rdeg   = (float*)(ws + 262144);
    int*            rowptr = (int*)(ws + 524288);
    int*            cursor = (int*)(ws + 786432);          // dead after csr_fill
    float*          pooled = (float*)(ws + 786432);        // aliases cursor: f32[64*256] = 64KB
    int*            csr    = (int*)(ws + 1048576);         // [800000]
    int*            d0list = (int*)(ws + 4259840);         // [50000]
    unsigned short* x_bf   = (unsigned short*)(ws + 4521984);    // [N_PAD][128]
    unsigned short* ns0_bf = (unsigned short*)(ws + 17334272);   // [N_PAD][128]
    unsigned short* h1_bf  = (unsigned short*)(ws + 30146560);   // [N_PAD][256]
    unsigned short* ns1_bf = (unsigned short*)(ws + 55771136);   // [N_PAD][256]
    unsigned short* h2_bf  = (unsigned short*)(ws + 81395712);   // [N_PAD][256]
    unsigned short* Wt0    = (unsigned short*)(ws + 107020288);  // [256][256]
    unsigned short* Wt1    = (unsigned short*)(ws + 107151360);  // [256][512]

    // zero degree counts + d0cnt
    hipMemsetAsync(ws, 0, 262144, stream);

    // CSR build (multi-block scan)
    deg_count_kernel<<<(N_EDGES + 255) / 256, 256, 0, stream>>>(src, deg);
    block_sum_kernel<<<NB_SCAN, SCAN_BLK, 0, stream>>>(deg, blocksum);
    block_offset_kernel<<<1, 64, 0, stream>>>(blocksum, blockoff);
    scan_phase_c_kernel<<<NB_SCAN, SCAN_BLK, 0, stream>>>(deg, blockoff, rowptr, cursor, rdeg, d0cnt, d0list);
    csr_fill_kernel<<<(N_EDGES + 255) / 256, 256, 0, stream>>>(src, dst, cursor, csr);

    // weight prep + x conversion
    prep_w_kernel<IN_DIM><<<(256 * 2 * IN_DIM + 255) / 256, 256, 0, stream>>>(Wg0, Wl0, Ws0, Wt0);
    prep_w_kernel<HIDDEN><<<(256 * 2 * HIDDEN + 255) / 256, 256, 0, stream>>>(Wg1, Wl1, Ws1, Wt1);
    cvt_bf16_kernel<<<(N_NODES * IN_DIM / 4 + 255) / 256, 256, 0, stream>>>(x, x_bf, N_NODES * IN_DIM / 4);

    // layer 0
    gather_mean_kernel<IN_DIM><<<(N_NODES + 3) / 4, 256, 0, stream>>>(rowptr, csr, rdeg, x_bf, ns0_bf);
    gemm_mfma_kernel<IN_DIM><<<(N_NODES + 127) / 128, 512, 0, stream>>>(x_bf, ns0_bf, Wt0, b0, h1_bf);
    fixup_kernel<float, IN_DIM><<<64, 256, 0, stream>>>(d0cnt, d0list, x, Wg0, b0, h1_bf);

    // layer 1
    gather_mean_kernel<HIDDEN><<<(N_NODES + 3) / 4, 256, 0, stream>>>(rowptr, csr, rdeg, h1_bf, ns1_bf);
    gemm_mfma_kernel<HIDDEN><<<(N_NODES + 127) / 128, 512, 0, stream>>>(h1_bf, ns1_bf, Wt1, b1, h2_bf);
    fixup_kernel<unsigned short, HIDDEN><<<64, 256, 0, stream>>>(d0cnt, d0list, h1_bf, Wg1, b1, h2_bf);

    // pool (cursor buffer is dead by now; pooled aliases it)
    hipMemsetAsync(pooled, 0, N_GRAPHS * HIDDEN * sizeof(float), stream);
    pool_partial_kernel<<<(N_NODES + 63) / 64, 256, 0, stream>>>(h2_bf, batch, pooled);
    classify_kernel<<<N_GRAPHS, HIDDEN, 0, stream>>>(pooled, batch, Wc, bc, (float*)d_out);
}

// Round 8
// 277.336 us; speedup vs baseline: 1.6883x; 1.0125x over previous
//
#include <hip/hip_runtime.h>

#define N_NODES 50000
#define N_PAD   50048          // padded row count (multiple of 128)
#define N_EDGES 800000
#define IN_DIM 128
#define HIDDEN 256
#define N_CLASSES 10
#define N_GRAPHS 64

#define SCAN_BLK 1024
#define NB_SCAN ((N_NODES + SCAN_BLK - 1) / SCAN_BLK)   // 49

typedef __attribute__((ext_vector_type(8))) short short8;
typedef __attribute__((ext_vector_type(4))) float f32x4;

__device__ __forceinline__ float bf2f(unsigned short h) {
    union { unsigned int u; float f; } v; v.u = ((unsigned int)h) << 16; return v.f;
}
__device__ __forceinline__ unsigned short f2bf(float f) {
    union { float f; unsigned int u; } v; v.f = f;
    unsigned int u = v.u;
    u += 0x7FFFu + ((u >> 16) & 1u);   // round to nearest even
    return (unsigned short)(u >> 16);
}

// ---------------- degree count ----------------
__global__ void deg_count_kernel(const int* __restrict__ src, int* __restrict__ deg) {
    int e = blockIdx.x * blockDim.x + threadIdx.x;
    if (e < N_EDGES) atomicAdd(&deg[src[e]], 1);
}

// ---------------- multi-block scan, phase A: per-block sums ----------------
__global__ __launch_bounds__(SCAN_BLK)
void block_sum_kernel(const int* __restrict__ deg, int* __restrict__ blocksum) {
    __shared__ int red[SCAN_BLK / 64];
    int i = blockIdx.x * SCAN_BLK + threadIdx.x;
    int v = (i < N_NODES) ? deg[i] : 0;
    #pragma unroll
    for (int off = 32; off; off >>= 1) v += __shfl_down(v, off, 64);
    if ((threadIdx.x & 63) == 0) red[threadIdx.x >> 6] = v;
    __syncthreads();
    if (threadIdx.x < 64) {
        int s = (threadIdx.x < SCAN_BLK / 64) ? red[threadIdx.x] : 0;
        #pragma unroll
        for (int off = 8; off; off >>= 1) s += __shfl_down(s, off, 64);
        if (threadIdx.x == 0) blocksum[blockIdx.x] = s;
    }
}

// ---------------- phase B: exclusive scan of block sums (one wave) ----------------
__global__ void block_offset_kernel(const int* __restrict__ blocksum, int* __restrict__ blockoff) {
    int lane = threadIdx.x;   // 64 threads
    int v = (lane < NB_SCAN) ? blocksum[lane] : 0;
    #pragma unroll
    for (int off = 1; off < 64; off <<= 1) {
        int t = __shfl_up(v, off, 64);
        if (lane >= off) v += t;
    }
    int ex = __shfl_up(v, 1, 64);
    if (lane == 0) ex = 0;
    if (lane < NB_SCAN) blockoff[lane] = ex;
}

// ---------------- phase C: local scan + outputs ----------------
__global__ __launch_bounds__(SCAN_BLK)
void scan_phase_c_kernel(const int* __restrict__ deg, const int* __restrict__ blockoff,
                         int* __restrict__ rowptr, int* __restrict__ cursor,
                         float* __restrict__ rdeg,
                         int* __restrict__ d0cnt, int* __restrict__ d0list) {
    __shared__ int buf[SCAN_BLK];
    int i = blockIdx.x * SCAN_BLK + threadIdx.x;
    int v = (i < N_NODES) ? deg[i] : 0;
    buf[threadIdx.x] = v;
    __syncthreads();
    #pragma unroll
    for (int off = 1; off < SCAN_BLK; off <<= 1) {
        int t = (threadIdx.x >= off) ? buf[threadIdx.x - off] : 0;
        __syncthreads();
        buf[threadIdx.x] += t;
        __syncthreads();
    }
    int incl = buf[threadIdx.x] + blockoff[blockIdx.x];
    if (i < N_NODES) {
        rowptr[i + 1] = incl;
        cursor[i] = incl - v;
        rdeg[i] = (v > 0) ? 1.0f / (float)v : 0.0f;
        if (v == 0) { int p = atomicAdd(d0cnt, 1); d0list[p] = i; }
        if (i == 0) rowptr[0] = 0;
    }
}

// ---------------- CSR fill ----------------
__global__ void csr_fill_kernel(const int* __restrict__ src, const int* __restrict__ dst,
                                int* __restrict__ cursor, int* __restrict__ csr) {
    int e = blockIdx.x * blockDim.x + threadIdx.x;
    if (e < N_EDGES) {
        int p = atomicAdd(&cursor[src[e]], 1);
        csr[p] = dst[e];
    }
}

// ---------------- fp32 -> bf16 convert (4 at a time) ----------------
__global__ void cvt_bf16_kernel(const float* __restrict__ in, unsigned short* __restrict__ out, int n4) {
    int i = blockIdx.x * blockDim.x + threadIdx.x;
    if (i >= n4) return;
    float4 v = reinterpret_cast<const float4*>(in)[i];
    ushort4 o;
    o.x = f2bf(v.x); o.y = f2bf(v.y); o.z = f2bf(v.z); o.w = f2bf(v.w);
    reinterpret_cast<ushort4*>(out)[i] = o;
}

// ---------------- weight prep: Wt[c][k] = bf16( k<D ? Wg[k][c]+Ws[k][c] : Wl[k-D][c] ) ----------------
template<int D>
__global__ void prep_w_kernel(const float* __restrict__ Wg, const float* __restrict__ Wl,
                              const float* __restrict__ Ws, unsigned short* __restrict__ Wt) {
    int i = blockIdx.x * blockDim.x + threadIdx.x;
    if (i >= 256 * 2 * D) return;
    int c = i / (2 * D), k = i % (2 * D);
    float v;
    if (k < D) v = Wg[(size_t)k * 256 + c] + Ws[(size_t)k * 256 + c];
    else       v = Wl[(size_t)(k - D) * 256 + c];
    Wt[i] = f2bf(v);
}

// ---------------- gather mean (bf16 row-major), one wave per node, uint4/lane ----------------
// D=256: 32 lanes cover a 512B row, 2 edge slots; D=128: 16 lanes cover 256B, 4 slots.
// Unroll 4: fetch 4 indices, then 4 independent row loads in flight per lane.
template<int D>
__global__ __launch_bounds__(256)
void gather_mean_kernel(const int* __restrict__ rowptr, const int* __restrict__ csr,
                        const float* __restrict__ rdeg,
                        const unsigned short* __restrict__ H, unsigned short* __restrict__ NS) {
    constexpr int LPR = D / 8;        // lanes per row (16 B each): 32 or 16
    constexpr int EPW = 64 / LPR;     // edge slots per wave: 2 or 4
    int node = blockIdx.x * 4 + (threadIdx.x >> 6);
    if (node >= N_NODES) return;
    const int lane = threadIdx.x & 63;
    const int sub = lane / LPR;       // edge slot
    const int sl  = lane % LPR;       // 16B chunk within row
    const int lo = rowptr[node], hi = rowptr[node + 1];
    const uint4* H4 = reinterpret_cast<const uint4*>(H);
    float a0=0.f,a1=0.f,a2=0.f,a3=0.f,a4=0.f,a5=0.f,a6=0.f,a7=0.f;
#define ACC8(v)                                        \
    do {                                               \
        a0 += bf2f((v).x & 0xFFFF); a1 += bf2f((v).x >> 16); \
        a2 += bf2f((v).y & 0xFFFF); a3 += bf2f((v).y >> 16); \
        a4 += bf2f((v).z & 0xFFFF); a5 += bf2f((v).z >> 16); \
        a6 += bf2f((v).w & 0xFFFF); a7 += bf2f((v).w >> 16); \
    } while (0)
    int j = lo;
    for (; j + 4 * EPW <= hi; j += 4 * EPW) {
        int d0 = csr[j + 0 * EPW + sub];
        int d1 = csr[j + 1 * EPW + sub];
        int d2 = csr[j + 2 * EPW + sub];
        int d3 = csr[j + 3 * EPW + sub];
        uint4 v0 = H4[(size_t)d0 * LPR + sl];
        uint4 v1 = H4[(size_t)d1 * LPR + sl];
        uint4 v2 = H4[(size_t)d2 * LPR + sl];
        uint4 v3 = H4[(size_t)d3 * LPR + sl];
        ACC8(v0); ACC8(v1); ACC8(v2); ACC8(v3);
    }
    for (; j + sub < hi; j += EPW) {
        uint4 v0 = H4[(size_t)csr[j + sub] * LPR + sl];
        ACC8(v0);
    }
#undef ACC8
    // reduce across edge slots (lanes differing in bits >= log2(LPR))
    #pragma unroll
    for (int off = LPR; off < 64; off <<= 1) {
        a0 += __shfl_xor(a0, off, 64);
        a1 += __shfl_xor(a1, off, 64);
        a2 += __shfl_xor(a2, off, 64);
        a3 += __shfl_xor(a3, off, 64);
        a4 += __shfl_xor(a4, off, 64);
        a5 += __shfl_xor(a5, off, 64);
        a6 += __shfl_xor(a6, off, 64);
        a7 += __shfl_xor(a7, off, 64);
    }
    if (sub == 0) {
        float r = rdeg[node];
        uint4 o;
        o.x = (unsigned int)f2bf(a0 * r) | ((unsigned int)f2bf(a1 * r) << 16);
        o.y = (unsigned int)f2bf(a2 * r) | ((unsigned int)f2bf(a3 * r) << 16);
        o.z = (unsigned int)f2bf(a4 * r) | ((unsigned int)f2bf(a5 * r) << 16);
        o.w = (unsigned int)f2bf(a6 * r) | ((unsigned int)f2bf(a7 * r) << 16);
        reinterpret_cast<uint4*>(NS)[(size_t)node * LPR + sl] = o;
    }
}

// ---------------- MFMA GEMM: OUT = elu( [X|NS] @ Wt^T + b ), Wt is [256][2D] bf16 ----------------
template<int D>
__global__ __launch_bounds__(512)
void gemm_mfma_kernel(const unsigned short* __restrict__ X, const unsigned short* __restrict__ NS,
                      const unsigned short* __restrict__ Wt, const float* __restrict__ bias,
                      unsigned short* __restrict__ OUT) {
    constexpr int KTOT = 2 * D;
    __shared__ __align__(16) unsigned short A_lds[128 * 64];
    __shared__ __align__(16) unsigned short B_lds[256 * 64];
    const int tid = threadIdx.x;
    const int lane = tid & 63;
    const int wid = tid >> 6;
    const int wm = wid >> 2, wn = wid & 3;
    const int rowbase = blockIdx.x * 128;

    f32x4 acc[4][4];
    #pragma unroll
    for (int i = 0; i < 4; ++i)
        #pragma unroll
        for (int j = 0; j < 4; ++j) acc[i][j] = (f32x4)0.0f;

    for (int kt = 0; kt < KTOT; kt += 64) {
        const unsigned short* Aseg = (kt < D) ? X : NS;
        const int kd0 = (kt < D) ? kt : kt - D;
        #pragma unroll
        for (int p = 0; p < 2; ++p) {
            int c = (p * 8 + wid) * 64 + lane;
            int row = c >> 3, sl = c & 7;
            int ss = sl ^ (row & 7);
            const unsigned short* g = Aseg + (size_t)(rowbase + row) * D + kd0 + ss * 8;
            unsigned short* l = &A_lds[(size_t)(p * 8 + wid) * 512];
            __builtin_amdgcn_global_load_lds((const __attribute__((address_space(1))) unsigned int*)g,
                                             (__attribute__((address_space(3))) unsigned int*)l, 16, 0, 0);
        }
        #pragma unroll
        for (int p = 0; p < 4; ++p) {
            int c = (p * 8 + wid) * 64 + lane;
            int br = c >> 3, sl = c & 7;
            int ss = sl ^ (br & 7);
            const unsigned short* g = Wt + (size_t)br * KTOT + kt + ss * 8;
            unsigned short* l = &B_lds[(size_t)(p * 8 + wid) * 512];
            __builtin_amdgcn_global_load_lds((const __attribute__((address_space(1))) unsigned int*)g,
                                             (__attribute__((address_space(3))) unsigned int*)l, 16, 0, 0);
        }
        __syncthreads();
        #pragma unroll
        for (int ks = 0; ks < 2; ++ks) {
            short8 a[4], b[4];
            int s = ks * 4 + (lane >> 4);
            #pragma unroll
            for (int f = 0; f < 4; ++f) {
                int row = wm * 64 + f * 16 + (lane & 15);
                a[f] = *reinterpret_cast<const short8*>(&A_lds[row * 64 + ((s ^ (row & 7)) << 3)]);
                int col = wn * 64 + f * 16 + (lane & 15);
                b[f] = *reinterpret_cast<const short8*>(&B_lds[col * 64 + ((s ^ (col & 7)) << 3)]);
            }
            #pragma unroll
            for (int fi = 0; fi < 4; ++fi)
                #pragma unroll
                for (int fj = 0; fj < 4; ++fj)
                    acc[fi][fj] = __builtin_amdgcn_mfma_f32_16x16x32_bf16(a[fi], b[fj], acc[fi][fj], 0, 0, 0);
        }
        __syncthreads();
    }

    float bv[4];
    #pragma unroll
    for (int fj = 0; fj < 4; ++fj) bv[fj] = bias[wn * 64 + fj * 16 + (lane & 15)];
    #pragma unroll
    for (int fi = 0; fi < 4; ++fi) {
        #pragma unroll
        for (int r = 0; r < 4; ++r) {
            int row = rowbase + wm * 64 + fi * 16 + (lane >> 4) * 4 + r;
            if (row < N_NODES) {
                #pragma unroll
                for (int fj = 0; fj < 4; ++fj) {
                    float z = acc[fi][fj][r] + bv[fj];
                    z = z > 0.f ? z : (expf(z) - 1.f);
                    OUT[(size_t)row * 256 + wn * 64 + fj * 16 + (lane & 15)] = f2bf(z);
                }
            }
        }
    }
}

// ---------------- fixup for degree-0 rows: OUT[row] = elu(X[row] @ Wg + b) ----------------
template<typename T, int D>
__global__ void fixup_kernel(const int* __restrict__ cnt, const int* __restrict__ list,
                             const T* __restrict__ X,
                             const float* __restrict__ Wg, const float* __restrict__ bias,
                             unsigned short* __restrict__ OUT) {
    int c = threadIdx.x;
    int n = *cnt;
    for (int i = blockIdx.x; i < n; i += gridDim.x) {
        int row = list[i];
        float acc = bias[c];
        for (int k = 0; k < D; ++k) {
            float xv;
            if constexpr (sizeof(T) == 4) xv = ((const float*)X)[(size_t)row * D + k];
            else                          xv = bf2f(((const unsigned short*)X)[(size_t)row * D + k]);
            acc = fmaf(xv, Wg[(size_t)k * 256 + c], acc);
        }
        acc = acc > 0.f ? acc : (expf(acc) - 1.f);
        OUT[(size_t)row * 256 + c] = f2bf(acc);
    }
}

// ---------------- pooling stage 1: per-block segmented accumulate -> atomicAdd ----------------
__global__ __launch_bounds__(256)
void pool_partial_kernel(const unsigned short* __restrict__ H, const int* __restrict__ batch,
                         float* __restrict__ pooled) {
    const int base = blockIdx.x * 64;
    const int t = threadIdx.x;
    float acc = 0.0f;
    int cur = batch[base];
    const int end = (base + 64 < N_NODES) ? base + 64 : N_NODES;
    for (int r = base; r < end; ++r) {
        int g = batch[r];
        if (g != cur) {
            atomicAdd(&pooled[cur * HIDDEN + t], acc);
            acc = 0.0f; cur = g;
        }
        acc += bf2f(H[(size_t)r * HIDDEN + t]);
    }
    atomicAdd(&pooled[cur * HIDDEN + t], acc);
}

// ---------------- pooling stage 2: divide + classifier ----------------
__global__ void classify_kernel(const float* __restrict__ pooled, const int* __restrict__ batch,
                                const float* __restrict__ Wc, const float* __restrict__ bc,
                                float* __restrict__ out) {
    __shared__ int s_lo, s_hi;
    __shared__ float pl[HIDDEN];
    int g = blockIdx.x;
    if (threadIdx.x == 0) {
        int lo = 0, hi = N_NODES;
        while (lo < hi) { int m = (lo + hi) >> 1; if (batch[m] < g) lo = m + 1; else hi = m; }
        s_lo = lo;
        int lo2 = lo, hi2 = N_NODES;
        while (lo2 < hi2) { int m = (lo2 + hi2) >> 1; if (batch[m] < g + 1) lo2 = m + 1; else hi2 = m; }
        s_hi = lo2;
    }
    __syncthreads();
    int t = threadIdx.x;
    float cnt = (float)(s_hi - s_lo);
    pl[t] = pooled[g * HIDDEN + t] / fmaxf(cnt, 1.0f);
    __syncthreads();
    if (t < N_CLASSES) {
        float accv = bc[t];
        #pragma unroll 4
        for (int k = 0; k < HIDDEN; ++k) accv = fmaf(pl[k], Wc[k * N_CLASSES + t], accv);
        out[g * N_CLASSES + t] = accv;
    }
}

extern "C" void kernel_launch(void* const* d_in, const int* in_sizes, int n_in,
                              void* d_out, int out_size, void* d_ws, size_t ws_size,
                              hipStream_t stream) {
    const float* x    = (const float*)d_in[0];
    const int*   ei   = (const int*)d_in[1];
    const int*   batch= (const int*)d_in[2];
    const float* Wg0  = (const float*)d_in[3];
    const float* Wl0  = (const float*)d_in[4];
    const float* Ws0  = (const float*)d_in[5];
    const float* b0   = (const float*)d_in[6];
    const float* Wg1  = (const float*)d_in[7];
    const float* Wl1  = (const float*)d_in[8];
    const float* Ws1  = (const float*)d_in[9];
    const float* b1   = (const float*)d_in[10];
    const float* Wc   = (const float*)d_in[11];
    const float* bc   = (const float*)d_in[12];
    const int* src = ei;
    const int* dst = ei + N_EDGES;

    char* ws = (char*)d_ws;
    int*            deg    = (int*)(ws + 0);               // [N_PAD]
    int*            d0cnt  = (int*)(ws + 200192);          // 1 int (inside memset region)
    int*            blocksum = (int*)(ws + 200704);        // [49]
    int*            blockoff = (int*)(ws + 201216);        // [49]
    float*          rdeg   = (float*)(ws + 262144);
    int*            rowptr = (int*)(ws + 524288);
    int*            cursor = (int*)(ws + 786432);          // dead after csr_fill
    float*          pooled = (float*)(ws + 786432);        // aliases cursor: f32[64*256] = 64KB
    int*            csr    = (int*)(ws + 1048576);         // [800000]
    int*            d0list = (int*)(ws + 4259840);         // [50000]
    unsigned short* x_bf   = (unsigned short*)(ws + 4521984);    // [N_PAD][128]
    unsigned short* ns0_bf = (unsigned short*)(ws + 17334272);   // [N_PAD][128]
    unsigned short* h1_bf  = (unsigned short*)(ws + 30146560);   // [N_PAD][256]
    unsigned short* ns1_bf = (unsigned short*)(ws + 55771136);   // [N_PAD][256]
    unsigned short* h2_bf  = (unsigned short*)(ws + 81395712);   // [N_PAD][256]
    unsigned short* Wt0    = (unsigned short*)(ws + 107020288);  // [256][256]
    unsigned short* Wt1    = (unsigned short*)(ws + 107151360);  // [256][512]

    // zero degree counts + d0cnt
    hipMemsetAsync(ws, 0, 262144, stream);

    // CSR build (multi-block scan)
    deg_count_kernel<<<(N_EDGES + 255) / 256, 256, 0, stream>>>(src, deg);
    block_sum_kernel<<<NB_SCAN, SCAN_BLK, 0, stream>>>(deg, blocksum);
    block_offset_kernel<<<1, 64, 0, stream>>>(blocksum, blockoff);
    scan_phase_c_kernel<<<NB_SCAN, SCAN_BLK, 0, stream>>>(deg, blockoff, rowptr, cursor, rdeg, d0cnt, d0list);
    csr_fill_kernel<<<(N_EDGES + 255) / 256, 256, 0, stream>>>(src, dst, cursor, csr);

    // weight prep + x conversion
    prep_w_kernel<IN_DIM><<<(256 * 2 * IN_DIM + 255) / 256, 256, 0, stream>>>(Wg0, Wl0, Ws0, Wt0);
    prep_w_kernel<HIDDEN><<<(256 * 2 * HIDDEN + 255) / 256, 256, 0, stream>>>(Wg1, Wl1, Ws1, Wt1);
    cvt_bf16_kernel<<<(N_NODES * IN_DIM / 4 + 255) / 256, 256, 0, stream>>>(x, x_bf, N_NODES * IN_DIM / 4);

    // layer 0
    gather_mean_kernel<IN_DIM><<<(N_NODES + 3) / 4, 256, 0, stream>>>(rowptr, csr, rdeg, x_bf, ns0_bf);
    gemm_mfma_kernel<IN_DIM><<<(N_NODES + 127) / 128, 512, 0, stream>>>(x_bf, ns0_bf, Wt0, b0, h1_bf);
    fixup_kernel<float, IN_DIM><<<64, 256, 0, stream>>>(d0cnt, d0list, x, Wg0, b0, h1_bf);

    // layer 1
    gather_mean_kernel<HIDDEN><<<(N_NODES + 3) / 4, 256, 0, stream>>>(rowptr, csr, rdeg, h1_bf, ns1_bf);
    gemm_mfma_kernel<HIDDEN><<<(N_NODES + 127) / 128, 512, 0, stream>>>(h1_bf, ns1_bf, Wt1, b1, h2_bf);
    fixup_kernel<unsigned short, HIDDEN><<<64, 256, 0, stream>>>(d0cnt, d0list, h1_bf, Wg1, b1, h2_bf);

    // pool (cursor buffer is dead by now; pooled aliases it)
    hipMemsetAsync(pooled, 0, N_GRAPHS * HIDDEN * sizeof(float), stream);
    pool_partial_kernel<<<(N_NODES + 63) / 64, 256, 0, stream>>>(h2_bf, batch, pooled);
    classify_kernel<<<N_GRAPHS, HIDDEN, 0, stream>>>(pooled, batch, Wc, bc, (float*)d_out);
}